// Round 12
// baseline (420.879 us; speedup 1.0000x reference)
//
#include <hip/hip_runtime.h>
#include <hip/hip_fp16.h>

#define C 4096
#define NN 110
#define NMT 7                // m-tiles of 16 (112 rows)
#define KBS (NMT * 512)      // halves per 32-k fragment block = 3584

typedef _Float16 f16x8 __attribute__((ext_vector_type(8)));
typedef float fx4 __attribute__((ext_vector_type(4)));
typedef unsigned long long ull;

// Fragment-major layout for fp16 A operands:
//   idx(n,c) = (c>>5)*KBS + (n>>4)*512 + (((c>>3)&3)*16 + (n&15))*8 + (c&7)
__device__ __forceinline__ size_t fragidx(int n, int c) {
    return (size_t)(c >> 5) * KBS + (n >> 4) * 512
         + (((c >> 3) & 3) * 16 + (n & 15)) * 8 + (c & 7);
}

// non-draining barrier: ds-visibility only; VMEM loads stay outstanding.
#define PIPE_BARRIER()                                                \
    do {                                                              \
        asm volatile("s_waitcnt lgkmcnt(0)" ::: "memory");            \
        __builtin_amdgcn_s_barrier();                                 \
        __builtin_amdgcn_sched_barrier(0);                            \
    } while (0)

// ---------------------------------------------------------------------------
// prep1: A1t = fragment-major fp16(x), rows >=110 zeroed.
// block 224 additionally builds adjacency bitmasks + degrees.
// ---------------------------------------------------------------------------
__global__ __launch_bounds__(256)
void prep1_kernel(const float* __restrict__ x, _Float16* __restrict__ A1t,
                  const int* __restrict__ adj, ull* __restrict__ mlo,
                  ull* __restrict__ mhi, float* __restrict__ degs) {
    if (blockIdx.x == 224) {                      // maskprep block
        int j = threadIdx.x;
        if (j < NN) {
            ull lo = 0, hi = 0; int dg = 0;
            for (int i = 0; i < 64; ++i) {
                int m = (adj[i * NN + j] != 0);
                lo |= ((ull)m) << i; dg += m;
            }
            for (int i = 64; i < NN; ++i) {
                int m = (adj[i * NN + j] != 0);
                hi |= ((ull)m) << (i - 64); dg += m;
            }
            mlo[j] = lo; mhi[j] = hi;
            degs[j] = (float)(dg > 0 ? dg : 1);
        }
        return;
    }
    int u = blockIdx.x * 256 + threadIdx.x;       // 0 .. 57343
    int kb  = u / 448;
    int rem = u - kb * 448;
    int mt  = rem >> 6;
    int L   = rem & 63;
    int n   = mt * 16 + (L & 15);
    int c   = kb * 32 + (L >> 4) * 8;
    f16x8 hv;
    if (n < NN) {
        float4 v0 = *(const float4*)(x + (size_t)n * C + c);
        float4 v1 = *(const float4*)(x + (size_t)n * C + c + 4);
        hv[0]=(_Float16)v0.x; hv[1]=(_Float16)v0.y; hv[2]=(_Float16)v0.z; hv[3]=(_Float16)v0.w;
        hv[4]=(_Float16)v1.x; hv[5]=(_Float16)v1.y; hv[6]=(_Float16)v1.z; hv[7]=(_Float16)v1.w;
    } else {
        for (int e = 0; e < 8; ++e) hv[e] = (_Float16)0.f;
    }
    *(f16x8*)(A1t + (size_t)u * 8) = hv;
}

// ---------------------------------------------------------------------------
// mm: Cacc[0:110, n0:n0+256] += A(frag-major, k-slice y) @ fp16(W slice)
//  KEY CHANGE vs all prior mm: W staging reads are 1KB-contiguous wave bursts
//  (64 lanes x float4 covering 1KB of ONE row), not 64B granules.
//  - tile: full M=112 x BN=256, BK=32; W read exactly ONCE (no m-split)
//  - thread owns k-granule w (rows w*8..w*8+7) at 4 cols -> f16x8 pack along k
//    -> 4 ds_write_b128, XOR slot key (c>>2)&3 (reads uniform 32B/bank = free)
//  - A-fragments direct global(L2)->VGPR (1KB contiguous), loaded per chunk
//  - lgkm-only barriers; B(it+1) loads stay in flight through MFMA(it)
//  - epilogue: atomicAdd into pre-zeroed Cacc (L2-resident, R6-proven cost)
// Block 256 thr = 4 waves; wave w -> cols w*64..+63. Grid (16, 32) = 512.
// ---------------------------------------------------------------------------
template<int NC>   // chunks of 32 k per slice: mm1=4, mm2=8
__global__ __launch_bounds__(256, 2)
void mm_kernel(const _Float16* __restrict__ A, const float* __restrict__ B,
               float* __restrict__ Cacc) {
    __shared__ __align__(16) _Float16 Bs[2][256 * 32];   // 2 x 16KB

    const int t   = threadIdx.x;
    const int n0  = blockIdx.x * 256;
    const int y   = blockIdx.y;
    const int w   = t >> 6;
    const int L   = t & 63;
    const int l15 = L & 15;
    const int q   = L >> 4;
    const int m   = t & 63;        // staging col-group

    fx4 acc[7][4];
#pragma unroll
    for (int mt = 0; mt < 7; ++mt)
#pragma unroll
        for (int nt = 0; nt < 4; ++nt)
            acc[mt][nt] = (fx4){0.f, 0.f, 0.f, 0.f};

    const float*    Bp  = B + (size_t)(y * NC * 32) * C + n0 + m * 4;
    const _Float16* ApL = A + (size_t)(y * NC) * KBS + L * 8;
    const _Float16* BsR = &Bs[0][0] + (w * 64) * 32;

    fx4   bva[8];          // staging: rows w*8..w*8+7 (k-granule w), 4 cols
    f16x8 af[7];           // A fragments, single-buffered (L2-resident)

#define LOADB(kc)                                                              \
    { _Pragma("unroll")                                                        \
      for (int p = 0; p < 8; ++p)                                              \
          bva[p] = *(const fx4*)(Bp + (size_t)((kc) * 32 + w * 8 + p) * C); }

#define COMMITB(buf)                                                           \
    { _Pragma("unroll")                                                        \
      for (int cj = 0; cj < 4; ++cj) {                                         \
          f16x8 hv;                                                            \
          _Pragma("unroll")                                                    \
          for (int e = 0; e < 8; ++e) hv[e] = (_Float16)bva[e][cj];            \
          *(f16x8*)(&Bs[buf][0] + (m * 4 + cj) * 32                            \
                    + ((w ^ (m & 3)) << 3)) = hv;                              \
      } }

#define LOADAF(kc)                                                             \
    { _Pragma("unroll")                                                        \
      for (int mt = 0; mt < 7; ++mt)                                           \
          af[mt] = *(const f16x8*)(ApL + (size_t)(kc) * KBS + mt * 512); }

    // prologue: chunk 0 staged (one-time vmcnt drain), A(0) issued
    LOADB(0);
    COMMITB(0);
    LOADAF(0);
    PIPE_BARRIER();

#pragma unroll
    for (int it = 0; it < NC; ++it) {
        if (it + 1 < NC) LOADB(it + 1);           // 1KB bursts, in flight thru MFMA
        __builtin_amdgcn_sched_barrier(0);
        // MFMA on chunk it: af regs + 4 swizzled ds_read_b128 per wave
#pragma unroll
        for (int nt = 0; nt < 4; ++nt) {
            f16x8 bf = *(const f16x8*)(BsR + (it & 1) * 8192 + (nt * 16 + l15) * 32
                            + ((q ^ ((l15 >> 2) & 3)) << 3));
#pragma unroll
            for (int mt = 0; mt < 7; ++mt)
                acc[mt][nt] = __builtin_amdgcn_mfma_f32_16x16x32_f16(
                    af[mt], bf, acc[mt][nt], 0, 0, 0);
        }
        if (it + 1 < NC) {
            LOADAF(it + 1);                        // af consumed; reload early
            COMMITB((it + 1) & 1);                 // waits B(it+1) only (A newer)
            PIPE_BARRIER();
            // hazard: writes buf[(it+1)&1]; last read iter it-1, separated by
            // iter it-1's barrier. lgkmcnt(0)+s_barrier publishes the writes.
        }
    }

    // epilogue: fp32 atomic accumulate (C/D: col=lane&15, row=q*4+reg)
#pragma unroll
    for (int mt = 0; mt < 7; ++mt)
#pragma unroll
        for (int nt = 0; nt < 4; ++nt) {
            const int col = n0 + w * 64 + nt * 16 + l15;
#pragma unroll
            for (int r = 0; r < 4; ++r) {
                int row = mt * 16 + q * 4 + r;
                if (row < NN)
                    atomicAdd(&Cacc[(size_t)row * C + col], acc[mt][nt][r]);
            }
        }
#undef LOADB
#undef COMMITB
#undef LOADAF
}

// ---------------------------------------------------------------------------
// agg: per 16-col tile, builds A3t = frag-major fp16([h+b2, aggr]) from h_raw
// ---------------------------------------------------------------------------
__global__ __launch_bounds__(256)
void agg_kernel(const float* __restrict__ h_raw, const ull* __restrict__ gmlo,
                const ull* __restrict__ gmhi, const float* __restrict__ gdegs,
                const float* __restrict__ b2, _Float16* __restrict__ A3t) {
    __shared__ float hb[NN * 16];
    const int t  = threadIdx.x;
    const int c0 = blockIdx.x * 16;

    for (int idx = t; idx < NN * 8; idx += 256) {
        int n = idx >> 3, cp = (idx & 7) << 1;
        float2 v = *(const float2*)(h_raw + (size_t)n * C + c0 + cp);
        float v0 = v.x + b2[c0 + cp];
        float v1 = v.y + b2[c0 + cp + 1];
        hb[n * 16 + cp]     = v0;
        hb[n * 16 + cp + 1] = v1;
        union { _Float16 h[2]; unsigned u; } pk;
        pk.h[0] = (_Float16)v0;
        pk.h[1] = (_Float16)v1;
        *(unsigned*)(A3t + fragidx(n, c0 + cp)) = pk.u;
    }
    // zero pad rows 110,111 for both halves of this c-tile
    if (t < 32) {
        int n  = 110 + ((t >> 3) & 1);
        int hs = t >> 4;
        int cp = (t & 7) << 1;
        *(unsigned*)(A3t + fragidx(n, hs * C + c0 + cp)) = 0u;
    }
    __syncthreads();
    for (int idx = t; idx < NN * 8; idx += 256) {
        int j = idx >> 3, cp = (idx & 7) << 1;
        ull lo = gmlo[j], hi = gmhi[j];
        float dg = gdegs[j];
        float a0 = 0.f, a1 = 0.f;
        for (int i = 0; i < 64; ++i)
            if ((lo >> i) & 1) { a0 += hb[i * 16 + cp]; a1 += hb[i * 16 + cp + 1]; }
        for (int i = 64; i < NN; ++i)
            if ((hi >> (i - 64)) & 1) { a0 += hb[i * 16 + cp]; a1 += hb[i * 16 + cp + 1]; }
        union { _Float16 h[2]; unsigned u; } pk;
        pk.h[0] = (_Float16)(a0 / dg);
        pk.h[1] = (_Float16)(a1 / dg);
        *(unsigned*)(A3t + fragidx(j, C + c0 + cp)) = pk.u;
    }
}

// ---------------------------------------------------------------------------
// fin: out[j,c] = sum_k Wl[j,k] * relu(z_raw[k,c]+b1[c]) + bl[j]
// ---------------------------------------------------------------------------
__global__ __launch_bounds__(256)
void fin_kernel(const float* __restrict__ z_raw, const float* __restrict__ b1,
                const float* __restrict__ Wl, const float* __restrict__ bl,
                float* __restrict__ out) {
    __shared__ float zs[NN * 64];
    const int t  = threadIdx.x;
    const int c0 = blockIdx.x * 64;
    const int c  = t & 63;

    for (int idx = t; idx < NN * 64; idx += 256) {
        int k = idx >> 6, cc = idx & 63;
        float v = z_raw[(size_t)k * C + c0 + cc] + b1[c0 + cc];
        zs[idx] = fmaxf(v, 0.f);
    }
    __syncthreads();
    for (int jj = 0; jj < 7; ++jj) {
        int j = blockIdx.y * 28 + jj * 4 + (t >> 6);
        if (j < NN) {
            float a = bl[j];
#pragma unroll 2
            for (int k = 0; k < NN; ++k)
                a += Wl[j * NN + k] * zs[k * 64 + c];   // Wl wave-uniform -> scalar
            out[(size_t)j * C + c0 + c] = a;
        }
    }
}

// ---------------------------------------------------------------------------
extern "C" void kernel_launch(void* const* d_in, const int* in_sizes, int n_in,
                              void* d_out, int out_size, void* d_ws, size_t ws_size,
                              hipStream_t stream) {
    const float* x   = (const float*)d_in[0];
    const int*   adj = (const int*)d_in[1];
    const float* W2  = (const float*)d_in[2];
    const float* b2  = (const float*)d_in[3];
    const float* W1  = (const float*)d_in[4];
    const float* b1  = (const float*)d_in[5];
    const float* Wl  = (const float*)d_in[6];
    const float* bl  = (const float*)d_in[7];
    float* out = (float*)d_out;

    char* ws = (char*)d_ws;
    float*    h_raw = (float*)(ws);                    // 110*4096 f32
    float*    z_raw = (float*)(ws + 1802240);          // 110*4096 f32
    _Float16* A1t   = (_Float16*)(ws + 3604480);       // frag-major fp16 (128 kb)
    _Float16* A3t   = (_Float16*)(ws + 4521984);       // frag-major fp16 (256 kb)
    ull*      mlo   = (ull*)(ws + 6356992);
    ull*      mhi   = (ull*)(ws + 6357872);
    float*    degs  = (float*)(ws + 6358752);
    // working set ~6.4MB + weights 201MB: fully L3-resident (no pack copies)

    hipMemsetAsync(d_ws, 0, 3604480, stream);          // zero h_raw, z_raw
    prep1_kernel<<<225, 256, 0, stream>>>(x, A1t, adj, mlo, mhi, degs);
    mm_kernel<4><<<dim3(16, 32), 256, 0, stream>>>(A1t, W2, h_raw);
    agg_kernel<<<C / 16, 256, 0, stream>>>(h_raw, mlo, mhi, degs, b2, A3t);
    mm_kernel<8><<<dim3(16, 32), 256, 0, stream>>>(A3t, W1, z_raw);
    fin_kernel<<<dim3(C / 64, 4), 256, 0, stream>>>(z_raw, b1, Wl, bl, out);
}

// Round 13
// 352.354 us; speedup vs baseline: 1.1945x; 1.1945x over previous
//
#include <hip/hip_runtime.h>
#include <hip/hip_fp16.h>

#define C 4096
#define NN 110
#define NMT 7                // m-tiles of 16 (112 rows)
#define KBS (NMT * 512)      // halves per 32-k fragment block = 3584
#define NSLICE 8             // K-split slices per GEMM

typedef _Float16 f16x8 __attribute__((ext_vector_type(8)));
typedef float fx4 __attribute__((ext_vector_type(4)));
typedef unsigned long long ull;

// Fragment-major layout for fp16 A operands:
//   idx(n,c) = (c>>5)*KBS + (n>>4)*512 + (((c>>3)&3)*16 + (n&15))*8 + (c&7)
__device__ __forceinline__ size_t fragidx(int n, int c) {
    return (size_t)(c >> 5) * KBS + (n >> 4) * 512
         + (((c >> 3) & 3) * 16 + (n & 15)) * 8 + (c & 7);
}

// async global->LDS copy, 16B per lane (global addr per-lane, LDS dest linear)
__device__ __forceinline__ void glds16(const float* g, float* l) {
    __builtin_amdgcn_global_load_lds(
        (const __attribute__((address_space(1))) void*)g,
        (__attribute__((address_space(3))) void*)l, 16, 0, 0);
}

// ---------------------------------------------------------------------------
// prep1: A1t = fragment-major fp16(x), rows >=110 zeroed.
// block 224 additionally builds adjacency bitmasks + degrees.
// ---------------------------------------------------------------------------
__global__ __launch_bounds__(256)
void prep1_kernel(const float* __restrict__ x, _Float16* __restrict__ A1t,
                  const int* __restrict__ adj, ull* __restrict__ mlo,
                  ull* __restrict__ mhi, float* __restrict__ degs) {
    if (blockIdx.x == 224) {                      // maskprep block
        int j = threadIdx.x;
        if (j < NN) {
            ull lo = 0, hi = 0; int dg = 0;
            for (int i = 0; i < 64; ++i) {
                int m = (adj[i * NN + j] != 0);
                lo |= ((ull)m) << i; dg += m;
            }
            for (int i = 64; i < NN; ++i) {
                int m = (adj[i * NN + j] != 0);
                hi |= ((ull)m) << (i - 64); dg += m;
            }
            mlo[j] = lo; mhi[j] = hi;
            degs[j] = (float)(dg > 0 ? dg : 1);
        }
        return;
    }
    int u = blockIdx.x * 256 + threadIdx.x;       // 0 .. 57343
    int kb  = u / 448;
    int rem = u - kb * 448;
    int mt  = rem >> 6;
    int L   = rem & 63;
    int n   = mt * 16 + (L & 15);
    int c   = kb * 32 + (L >> 4) * 8;
    f16x8 hv;
    if (n < NN) {
        float4 v0 = *(const float4*)(x + (size_t)n * C + c);
        float4 v1 = *(const float4*)(x + (size_t)n * C + c + 4);
        hv[0]=(_Float16)v0.x; hv[1]=(_Float16)v0.y; hv[2]=(_Float16)v0.z; hv[3]=(_Float16)v0.w;
        hv[4]=(_Float16)v1.x; hv[5]=(_Float16)v1.y; hv[6]=(_Float16)v1.z; hv[7]=(_Float16)v1.w;
    } else {
        for (int e = 0; e < 8; ++e) hv[e] = (_Float16)0.f;
    }
    *(f16x8*)(A1t + (size_t)u * 8) = hv;
}

// ---------------------------------------------------------------------------
// mm: part[y] = A(frag-major fp16, slice y) @ fp16(B fp32 slice)
//  R7 structure with ONE change: B staged via global_load_lds (16B/lane DMA,
//  no VGPR round-trip), fp32 in LDS, TRIPLE-buffered (glds issued 2 iters
//  ahead), counted vmcnt(18) before each barrier (never drains to 0).
//  Correctness: af(it)'s compiler-emitted vmcnt wait transitively retires
//  glds(it+1) (issued earlier in iter it-1); each wave's own vmcnt precedes
//  the s_barrier that other waves rely on for LDS visibility.
//  A-fragments direct global(L2)->VGPR, reg-dbuf (R7-proven).
//  B-fragments: 8x ds_read_b32 from fp32 LDS + cvt (4-way bank alias, cheap).
// Block 256 thr = 4 waves, tile 112(m) x 64(n); grid (64, NSLICE) = 512.
// ---------------------------------------------------------------------------
template<int NC>
__global__ __launch_bounds__(256, 2)
void mm_kernel(const _Float16* __restrict__ A, const float* __restrict__ B,
               float* __restrict__ Cpart) {
    __shared__ __align__(16) float Bs[3][64 * 64];   // 3 x 16KB fp32 [row][col]

    const int t   = threadIdx.x;
    const int j0  = blockIdx.x * 64;
    const int y   = blockIdx.y;
    const int w   = t >> 6;
    const int L   = t & 63;
    const int l15 = L & 15;
    const int q   = L >> 4;

    fx4 acc[7];
#pragma unroll
    for (int mt = 0; mt < 7; ++mt) acc[mt] = (fx4){0.f, 0.f, 0.f, 0.f};

    // glds source: wave w stages rows w*16 .. w*16+15 of each 64-row chunk;
    // instr i covers 4 rows (lane L -> row i*4 + L/16, cols (L&15)*4 ..+3)
    const float*    gB  = B + (size_t)(y * NC * 64 + w * 16 + (L >> 4)) * C
                        + j0 + (L & 15) * 4;
    const _Float16* ApL = A + (size_t)(y * NC * 2) * KBS + L * 8;

    f16x8 af[2][2][7];     // [regbuf][s][mt] — static indices after unroll

#define GLDS(ch, bufi)                                                         \
    { _Pragma("unroll")                                                        \
      for (int i = 0; i < 4; ++i)                                              \
          glds16(gB + (size_t)((ch) * 64 + i * 4) * C,                         \
                 &Bs[bufi][(w * 16 + i * 4) * 64]); }

#define LOADAF(buf, ch)                                                        \
    { _Pragma("unroll")                                                        \
      for (int s = 0; s < 2; ++s)                                              \
          _Pragma("unroll")                                                    \
          for (int mt = 0; mt < 7; ++mt)                                       \
              af[buf][s][mt] = *(const f16x8*)(ApL                             \
                  + (size_t)((ch) * 2 + s) * KBS + mt * 512); }

    // prologue: glds chunk0->buf0, chunk1->buf1, A(0); wait chunk0 only
    GLDS(0, 0);
    GLDS(1, 1);
    LOADAF(0, 0);
    asm volatile("s_waitcnt vmcnt(18)" ::: "memory");   // retire glds(0); 18 newer live
    __builtin_amdgcn_sched_barrier(0);
    __builtin_amdgcn_s_barrier();
    __builtin_amdgcn_sched_barrier(0);

#pragma unroll
    for (int it = 0; it < NC; ++it) {
        if (it + 2 < NC) GLDS(it + 2, (it + 2) % 3);    // 2-iter-ahead DMA
        if (it + 1 < NC) LOADAF((it + 1) & 1, it + 1);
        __builtin_amdgcn_sched_barrier(0);
        // MFMA on chunk it: fragments from fp32 LDS + af regs
#pragma unroll
        for (int s = 0; s < 2; ++s) {
            const float* bp = &Bs[it % 3][(s * 32 + q * 8) * 64 + w * 16 + l15];
            f16x8 bf;
#pragma unroll
            for (int e = 0; e < 8; ++e) bf[e] = (_Float16)bp[e * 64];
#pragma unroll
            for (int mt = 0; mt < 7; ++mt)
                acc[mt] = __builtin_amdgcn_mfma_f32_16x16x32_f16(
                    af[it & 1][s][mt], bf, acc[mt], 0, 0, 0);
        }
        if (it + 1 < NC) {
            // own glds(it+1) complete (counted — glds(it+2)+af(it+1)=18 stay live)
            asm volatile("s_waitcnt vmcnt(18)" ::: "memory");
            __builtin_amdgcn_sched_barrier(0);
            __builtin_amdgcn_s_barrier();
            __builtin_amdgcn_sched_barrier(0);
            // hazard: glds(it+2) targets buf[(it+2)%3], last read iter it-1,
            // separated by iter it-1's barrier. No ds_writes -> no lgkm needed.
        }
    }

    // epilogue: plain coalesced stores of this K-slice's partial tile
    float* Cp = Cpart + (size_t)y * (NN * C) + j0 + w * 16 + l15;
#pragma unroll
    for (int mt = 0; mt < 7; ++mt)
#pragma unroll
        for (int r = 0; r < 4; ++r) {
            int row = mt * 16 + q * 4 + r;
            if (row < NN)
                Cp[(size_t)row * C] = acc[mt][r];
        }
#undef GLDS
#undef LOADAF
}

// ---------------------------------------------------------------------------
// agg: per 16-col tile; reduces the 8 h-partials (+b2) in-flight, builds
// A3t = frag-major fp16([h, aggr]) [112][8192]
// ---------------------------------------------------------------------------
__global__ __launch_bounds__(256)
void agg_kernel(const float* __restrict__ hpart, const ull* __restrict__ gmlo,
                const ull* __restrict__ gmhi, const float* __restrict__ gdegs,
                const float* __restrict__ b2, _Float16* __restrict__ A3t) {
    __shared__ float hb[NN * 16];
    const int t  = threadIdx.x;
    const int c0 = blockIdx.x * 16;

    for (int idx = t; idx < NN * 8; idx += 256) {
        int n = idx >> 3, cp = (idx & 7) << 1;
        float v0 = b2[c0 + cp], v1 = b2[c0 + cp + 1];
#pragma unroll
        for (int p = 0; p < NSLICE; ++p) {
            float2 v = *(const float2*)(hpart + (size_t)p * (NN * C)
                                        + (size_t)n * C + c0 + cp);
            v0 += v.x; v1 += v.y;
        }
        hb[n * 16 + cp]     = v0;
        hb[n * 16 + cp + 1] = v1;
        union { _Float16 h[2]; unsigned u; } pk;
        pk.h[0] = (_Float16)v0;
        pk.h[1] = (_Float16)v1;
        *(unsigned*)(A3t + fragidx(n, c0 + cp)) = pk.u;
    }
    // zero pad rows 110,111 for both halves of this c-tile
    if (t < 32) {
        int n  = 110 + ((t >> 3) & 1);
        int hs = t >> 4;
        int cp = (t & 7) << 1;
        *(unsigned*)(A3t + fragidx(n, hs * C + c0 + cp)) = 0u;
    }
    __syncthreads();
    for (int idx = t; idx < NN * 8; idx += 256) {
        int j = idx >> 3, cp = (idx & 7) << 1;
        ull lo = gmlo[j], hi = gmhi[j];
        float dg = gdegs[j];
        float a0 = 0.f, a1 = 0.f;
        for (int i = 0; i < 64; ++i)
            if ((lo >> i) & 1) { a0 += hb[i * 16 + cp]; a1 += hb[i * 16 + cp + 1]; }
        for (int i = 64; i < NN; ++i)
            if ((hi >> (i - 64)) & 1) { a0 += hb[i * 16 + cp]; a1 += hb[i * 16 + cp + 1]; }
        union { _Float16 h[2]; unsigned u; } pk;
        pk.h[0] = (_Float16)(a0 / dg);
        pk.h[1] = (_Float16)(a1 / dg);
        *(unsigned*)(A3t + fragidx(j, C + c0 + cp)) = pk.u;
    }
}

// ---------------------------------------------------------------------------
// zred: z_raw = sum of 8 z-partials (float4 streaming)
// ---------------------------------------------------------------------------
__global__ __launch_bounds__(256)
void zred_kernel(const float* __restrict__ zpart, float* __restrict__ z_raw) {
    int idx = blockIdx.x * 256 + threadIdx.x;     // float4 units: 110*1024
    if (idx < NN * (C / 4)) {
        fx4 s = (fx4){0.f, 0.f, 0.f, 0.f};
#pragma unroll
        for (int p = 0; p < NSLICE; ++p) {
            fx4 v = *(const fx4*)(zpart + (size_t)p * (NN * C) + (size_t)idx * 4);
            s.x += v.x; s.y += v.y; s.z += v.z; s.w += v.w;
        }
        *(fx4*)(z_raw + (size_t)idx * 4) = s;
    }
}

// ---------------------------------------------------------------------------
// fin: out[j,c] = sum_k Wl[j,k] * relu(z_raw[k,c]+b1[c]) + bl[j]
// ---------------------------------------------------------------------------
__global__ __launch_bounds__(256)
void fin_kernel(const float* __restrict__ z_raw, const float* __restrict__ b1,
                const float* __restrict__ Wl, const float* __restrict__ bl,
                float* __restrict__ out) {
    __shared__ float zs[NN * 64];
    const int t  = threadIdx.x;
    const int c0 = blockIdx.x * 64;
    const int c  = t & 63;

    for (int idx = t; idx < NN * 64; idx += 256) {
        int k = idx >> 6, cc = idx & 63;
        float v = z_raw[(size_t)k * C + c0 + cc] + b1[c0 + cc];
        zs[idx] = fmaxf(v, 0.f);
    }
    __syncthreads();
    for (int jj = 0; jj < 7; ++jj) {
        int j = blockIdx.y * 28 + jj * 4 + (t >> 6);
        if (j < NN) {
            float a = bl[j];
#pragma unroll 2
            for (int k = 0; k < NN; ++k)
                a += Wl[j * NN + k] * zs[k * 64 + c];   // Wl wave-uniform -> scalar
            out[(size_t)j * C + c0 + c] = a;
        }
    }
}

// ---------------------------------------------------------------------------
extern "C" void kernel_launch(void* const* d_in, const int* in_sizes, int n_in,
                              void* d_out, int out_size, void* d_ws, size_t ws_size,
                              hipStream_t stream) {
    const float* x   = (const float*)d_in[0];
    const int*   adj = (const int*)d_in[1];
    const float* W2  = (const float*)d_in[2];
    const float* b2  = (const float*)d_in[3];
    const float* W1  = (const float*)d_in[4];
    const float* b1  = (const float*)d_in[5];
    const float* Wl  = (const float*)d_in[6];
    const float* bl  = (const float*)d_in[7];
    float* out = (float*)d_out;

    char* ws = (char*)d_ws;
    float*    hpart = (float*)(ws);                    // 8 x 110*4096 f32
    float*    zpart = (float*)(ws + 14417920);         // 8 x 110*4096 f32
    float*    z_raw = (float*)(ws + 28835840);         // 110*4096 f32
    _Float16* A1t   = (_Float16*)(ws + 30638080);      // frag-major fp16
    _Float16* A3t   = (_Float16*)(ws + 31555584);      // frag-major fp16
    ull*      mlo   = (ull*)(ws + 33390592);
    ull*      mhi   = (ull*)(ws + 33391472);
    float*    degs  = (float*)(ws + 33392352);

    prep1_kernel<<<225, 256, 0, stream>>>(x, A1t, adj, mlo, mhi, degs);
    mm_kernel<8><<<dim3(64, NSLICE), 256, 0, stream>>>(A1t, W2, hpart);
    agg_kernel<<<C / 16, 256, 0, stream>>>(hpart, mlo, mhi, degs, b2, A3t);
    mm_kernel<16><<<dim3(64, NSLICE), 256, 0, stream>>>(A3t, W1, zpart);
    zred_kernel<<<440, 256, 0, stream>>>(zpart, z_raw);
    fin_kernel<<<dim3(C / 64, 4), 256, 0, stream>>>(z_raw, b1, Wl, bl, out);
}